// Round 2
// baseline (259.058 us; speedup 1.0000x reference)
//
#include <hip/hip_runtime.h>

// SNN forward scan: B=64, N=1024, T=512. Row = (b*N+n), x[row*512 + t].
//
// R9: 512-B granules (CHUNK=128) to attack DRAM channel concentration.
// Theory: row stride 2 KiB = 8x the ~256-B channel interleave, so each
// chunk-phase's per-row 256-B granules (R7/R8) concentrated on nch/8
// channels. Doubling the per-row contiguous run to 512 B halves the
// concentration. To fit LDS in 64 KiB static (2 blocks/CU):
//   - spikes written IN-PLACE over consumed x (outbuf eliminated);
//     buffer lifecycle: stage(c) @ phase c-1 -> compute(c) in-place @ c
//     -> drain(c) @ c+1. drain(k-1)+stage(k+1) share the complement
//     buffer within a phase, ordered inside one io wave (lgkmcnt(0)
//     between reads and overwrites). ONE barrier per chunk (was two).
//   - XOR bank swizzle col^(row&31) replaces +1 padding: compute reads
//     2-way (free), io b32 writes ~4-way (negligible vs HBM phase).
// LDS = 2 x 64 x 128 x 4 B = 65536 B exactly -> 2 blocks/CU.
// NT stores kept (R8: -9% in-kernel).
// Predicted: dur 85.7 -> 66-74 us if channel theory right; neutral
// (83-92) falsifies 512-B granule hypothesis -> pivot to rotation.
//
// Numerics: BIT-EXACT vs float32 NumPy reference (0/1 threshold output —
// one ulp flip cascades). __fmul_rn/__fadd_rn + contract(off).
#pragma clang fp contract(off)

#define ROWS    64                    // rows per block (1 compute wave)
#define T_LEN   512
#define CHUNK   128                   // timesteps per tile (512 B/row contiguous)
#define NCHUNK  (T_LEN / CHUNK)       // 4
#define NV      16                    // float4 per io-lane per chunk (32 rows/wave)
#define NPARAM  1024
#define BUF_FLOATS (ROWS * CHUNK)     // 8192 floats per buffer

typedef float f4_nt __attribute__((ext_vector_type(4)));

// lgkmcnt(0)-only barrier: LDS visibility without the vmcnt(0) drain.
#define BARRIER() asm volatile("s_waitcnt lgkmcnt(0)\n\ts_barrier" ::: "memory")

__global__ __launch_bounds__(192) void snn_fwd(
    const float* __restrict__ x,
    const float* __restrict__ beta,
    const float* __restrict__ p,
    const float* __restrict__ bparam,
    float* __restrict__ out)
{
    __shared__ float smem[2][BUF_FLOATS];   // 65536 B exactly

    const int tid     = threadIdx.x;
    const int wid     = tid >> 6;       // 0=compute, 1=io rows 0-31, 2=io rows 32-63
    const int lane    = tid & 63;
    const int rowBase = blockIdx.x * ROWS;

    const float4* __restrict__ xv = (const float4*)x;  // row stride 128 float4
    float4* __restrict__ ov       = (float4*)out;

    // io mapping: lane = r2*32 + t32. One instr: rows {rw + 2*it}, 32 float4
    // (=512 B) CONTIGUOUS per row. Chunk k adds k*32 float4.
    const int t32 = lane & 31;
    const int r2  = lane >> 5;
    const int rw  = (wid > 0 ? (wid - 1) * 32 : 0) + r2;     // io wave's row
    const int gq  = (rowBase + rw) * (T_LEN / 4) + t32;      // float4 units

    // compute state
    float mem = 0.0f, refac = 2.0f, a = 0.0f, vth = 1.0f, ps = 0.0f;
    float beta_c = 0.f, p_c = 0.f, b_c = 0.f;
    const int crow = lane * CHUNK;     // compute lane's LDS row base
    const int cxm  = lane & 31;        // compute lane's XOR swizzle

    if (wid == 0) {
        const int n = (rowBase + lane) & (NPARAM - 1);
        beta_c = fminf(fmaxf(beta[n], 0.001f), 0.999f);
        p_c    = fminf(fabsf(p[n]), 0.999f);
        b_c    = fminf(fmaxf(fabsf(bparam[n]), 0.001f), 1.0f);
    }

    auto step = [&](float xt) -> float {
        refac = (ps > 0.0f) ? 0.0f : refac;           // spike-triggered reset
        const float ic = (refac < 2.0f) ? 0.0f : xt;  // refractory input mask
        refac += 1.0f;
        const float nm   = __fadd_rn(__fmul_rn(mem, beta_c), ic);  // integrate
        const float diff = __fsub_rn(nm, vth);
        const float s    = (diff > 0.0f) ? 1.0f : 0.0f;
        mem = (diff > 0.0f) ? 0.0f : nm;              // reset-to-zero on spike
        a   = __fadd_rn(__fmul_rn(p_c, a), s);        // adaptation
        vth = __fadd_rn(1.0f, __fmul_rn(b_c, a));     // adaptive threshold
        ps  = s;
        return s;
    };

    float4 ld[NV];  // io wave's register pipeline (one chunk ahead)

    auto loadChunk = [&](int k) {
        const int base = gq + k * (CHUNK / 4);
        #pragma unroll
        for (int it = 0; it < NV; ++it)
            ld[it] = xv[base + it * 2 * (T_LEN / 4)];  // +2 rows per it
    };
    auto stage = [&](float* buf) {   // b32 scatter, col ^ (row&31) swizzle
        #pragma unroll
        for (int it = 0; it < NV; ++it) {
            const int row = rw + 2 * it;
            const int o   = row * CHUNK;
            const int xm  = row & 31;
            const int c0  = t32 * 4;
            buf[o + ((c0 + 0) ^ xm)] = ld[it].x;
            buf[o + ((c0 + 1) ^ xm)] = ld[it].y;
            buf[o + ((c0 + 2) ^ xm)] = ld[it].z;
            buf[o + ((c0 + 3) ^ xm)] = ld[it].w;
        }
    };
    auto drain = [&](const float* buf, int k) {  // spikes -> global, NT, 512 B/row
        const int base = gq + k * (CHUNK / 4);
        #pragma unroll
        for (int it = 0; it < NV; ++it) {
            const int row = rw + 2 * it;
            const int o   = row * CHUNK;
            const int xm  = row & 31;
            const int c0  = t32 * 4;
            float4 sv;
            sv.x = buf[o + ((c0 + 0) ^ xm)];
            sv.y = buf[o + ((c0 + 1) ^ xm)];
            sv.z = buf[o + ((c0 + 2) ^ xm)];
            sv.w = buf[o + ((c0 + 3) ^ xm)];
            __builtin_nontemporal_store(
                *reinterpret_cast<f4_nt*>(&sv),
                reinterpret_cast<f4_nt*>(&ov[base + it * 2 * (T_LEN / 4)]));
        }
    };

    // preamble: chunk 0 staged into buf0; chunk 1 in regs (in flight)
    if (wid != 0) {
        loadChunk(0);
        stage(smem[0]);
        loadChunk(1);
    }
    BARRIER();

    #pragma unroll 1
    for (int k = 0; k < NCHUNK; ++k) {
        float* A = smem[k & 1];        // chunk k: computed in-place this phase
        float* B = smem[(k & 1) ^ 1];  // holds spikes(k-1), then x(k+1)
        if (wid == 0) {
            #pragma unroll
            for (int t = 0; t < CHUNK; ++t) {
                const int idx = crow + (t ^ cxm);
                const float s = step(A[idx]);
                A[idx] = s;            // spike overwrites consumed x
            }
        } else {
            if (k > 0) drain(B, k - 1);               // spikes from phase k-1
            // ensure drain's LDS reads retired before overwriting B
            asm volatile("s_waitcnt lgkmcnt(0)" ::: "memory");
            if (k + 1 < NCHUNK) stage(B);             // regs loaded one phase ago
            if (k + 2 < NCHUNK) loadChunk(k + 2);     // refill register pipeline
        }
        BARRIER();  // stage(k+1)/spikes(k) visible; drain(k-1) done before reuse
    }
    if (wid != 0) drain(smem[(NCHUNK - 1) & 1], NCHUNK - 1);
}

extern "C" void kernel_launch(void* const* d_in, const int* in_sizes, int n_in,
                              void* d_out, int out_size, void* d_ws, size_t ws_size,
                              hipStream_t stream) {
    const float* x    = (const float*)d_in[0];
    const float* beta = (const float*)d_in[1];
    const float* p    = (const float*)d_in[2];
    const float* b    = (const float*)d_in[3];
    float* out        = (float*)d_out;

    const int BN = 64 * 1024;  // rows
    snn_fwd<<<dim3(BN / ROWS), dim3(192), 0, stream>>>(x, beta, p, b, out);
}